// Round 1
// baseline (188.021 us; speedup 1.0000x reference)
//
#include <hip/hip_runtime.h>
#include <math.h>

#define HW    224
#define OW    223
#define FLAT  (OW * OW)   // 49729
#define NB    1024        // batch
#define AD    4           // ATTN_DIM

// ---------------------------------------------------------------------------
// Kernel 1: fused conv2d(k=2, VALID) + sigmoid + embed projection.
// One block per batch image; 256 threads stride over the 223x223 positions,
// each accumulating 4 partial dot products (one per embed channel).
// embedded[b*4 + c] = sum_p sigmoid(conv(b,p)) * embed_w[c*FLAT + p] + embed_b[c]
// ---------------------------------------------------------------------------
__global__ __launch_bounds__(256) void conv_embed_kernel(
    const float* __restrict__ x, const float* __restrict__ conv_w,
    const float* __restrict__ conv_b, const float* __restrict__ embed_w,
    const float* __restrict__ embed_b, float* __restrict__ embedded)
{
    const int b   = blockIdx.x;
    const int tid = threadIdx.x;

    const float w00 = conv_w[0], w01 = conv_w[1];
    const float w10 = conv_w[2], w11 = conv_w[3];
    const float cb  = conv_b[0];

    const float* __restrict__ xb  = x + (size_t)b * (HW * HW);
    const float* __restrict__ ew0 = embed_w;
    const float* __restrict__ ew1 = embed_w + FLAT;
    const float* __restrict__ ew2 = embed_w + 2 * FLAT;
    const float* __restrict__ ew3 = embed_w + 3 * FLAT;

    float a0 = 0.f, a1 = 0.f, a2 = 0.f, a3 = 0.f;

    for (int p = tid; p < FLAT; p += 256) {
        unsigned up = (unsigned)p;
        unsigned i  = up / 223u;          // magic-mul division
        unsigned j  = up - i * 223u;
        const float* xr = xb + i * HW + j;
        float z = w00 * xr[0] + w01 * xr[1] + w10 * xr[HW] + w11 * xr[HW + 1] + cb;
        float s = 1.0f / (1.0f + __expf(-z));   // sigmoid, CONV_THRESHOLD = 0
        a0 += s * ew0[p];
        a1 += s * ew1[p];
        a2 += s * ew2[p];
        a3 += s * ew3[p];
    }

    // wave (64-lane) reduction
    #pragma unroll
    for (int off = 32; off > 0; off >>= 1) {
        a0 += __shfl_down(a0, off, 64);
        a1 += __shfl_down(a1, off, 64);
        a2 += __shfl_down(a2, off, 64);
        a3 += __shfl_down(a3, off, 64);
    }

    __shared__ float red[4][4];   // 4 waves x 4 channels
    const int wid  = tid >> 6;
    const int lane = tid & 63;
    if (lane == 0) {
        red[wid][0] = a0; red[wid][1] = a1; red[wid][2] = a2; red[wid][3] = a3;
    }
    __syncthreads();
    if (tid == 0) {
        float r0 = red[0][0] + red[1][0] + red[2][0] + red[3][0] + embed_b[0];
        float r1 = red[0][1] + red[1][1] + red[2][1] + red[3][1] + embed_b[1];
        float r2 = red[0][2] + red[1][2] + red[2][2] + red[3][2] + embed_b[2];
        float r3 = red[0][3] + red[1][3] + red[2][3] + red[3][3] + embed_b[3];
        float4* e4 = (float4*)(embedded + (size_t)b * 4);
        *e4 = make_float4(r0, r1, r2, r3);
    }
}

// ---------------------------------------------------------------------------
// Kernel 2: q = e @ rotation, k = e @ entangle   (tiny: 1024 x 4 @ 4 x 4)
// ---------------------------------------------------------------------------
__global__ __launch_bounds__(256) void qk_kernel(
    const float* __restrict__ embedded, const float* __restrict__ rot,
    const float* __restrict__ ent, float* __restrict__ q, float* __restrict__ k)
{
    int b = blockIdx.x * 256 + threadIdx.x;
    if (b >= NB) return;
    float4 ev = ((const float4*)embedded)[b];
    float qv[4], kv[4];
    #pragma unroll
    for (int c = 0; c < 4; ++c) {
        qv[c] = ev.x * rot[0 * 4 + c] + ev.y * rot[1 * 4 + c]
              + ev.z * rot[2 * 4 + c] + ev.w * rot[3 * 4 + c];
        kv[c] = ev.x * ent[0 * 4 + c] + ev.y * ent[1 * 4 + c]
              + ev.z * ent[2 * 4 + c] + ev.w * ent[3 * 4 + c];
    }
    ((float4*)q)[b] = make_float4(qv[0], qv[1], qv[2], qv[3]);
    ((float4*)k)[b] = make_float4(kv[0], kv[1], kv[2], kv[3]);
}

// ---------------------------------------------------------------------------
// Kernel 3: per-row softmax attention + mean + sigmoid -> out [NB, 2]
// One block per query row r; K and E staged in LDS; online softmax.
// ---------------------------------------------------------------------------
__global__ __launch_bounds__(256) void attn_kernel(
    const float* __restrict__ embedded, const float* __restrict__ q,
    const float* __restrict__ k, float* __restrict__ out)
{
    __shared__ float4 k_lds[NB];
    __shared__ float4 e_lds[NB];
    const int r   = blockIdx.x;
    const int tid = threadIdx.x;

    for (int c = tid; c < NB; c += 256) {
        k_lds[c] = ((const float4*)k)[c];
        e_lds[c] = ((const float4*)embedded)[c];
    }
    __syncthreads();

    const float4 qr = ((const float4*)q)[r];

    float m = -INFINITY, l = 0.f;
    float a0 = 0.f, a1 = 0.f, a2 = 0.f, a3 = 0.f;

    for (int c = tid; c < NB; c += 256) {   // exactly 4 iterations per thread
        float4 kc = k_lds[c];
        float s = 0.5f * (qr.x * kc.x + qr.y * kc.y + qr.z * kc.z + qr.w * kc.w);
        float mn    = fmaxf(m, s);
        float scale = __expf(m - mn);       // exp(-inf)=0 on first iter
        float p     = __expf(s - mn);
        float4 ec = e_lds[c];
        l  = l  * scale + p;
        a0 = a0 * scale + p * ec.x;
        a1 = a1 * scale + p * ec.y;
        a2 = a2 * scale + p * ec.z;
        a3 = a3 * scale + p * ec.w;
        m = mn;
    }

    // merge online-softmax states across the 64-lane wave
    #pragma unroll
    for (int off = 32; off > 0; off >>= 1) {
        float m2 = __shfl_down(m,  off, 64);
        float l2 = __shfl_down(l,  off, 64);
        float b0 = __shfl_down(a0, off, 64);
        float b1 = __shfl_down(a1, off, 64);
        float b2 = __shfl_down(a2, off, 64);
        float b3 = __shfl_down(a3, off, 64);
        float mn = fmaxf(m, m2);
        float s1 = __expf(m - mn), s2 = __expf(m2 - mn);
        l  = l  * s1 + l2 * s2;
        a0 = a0 * s1 + b0 * s2;
        a1 = a1 * s1 + b1 * s2;
        a2 = a2 * s1 + b2 * s2;
        a3 = a3 * s1 + b3 * s2;
        m = mn;
    }

    __shared__ float wred[4][6];
    const int wid  = tid >> 6;
    const int lane = tid & 63;
    if (lane == 0) {
        wred[wid][0] = m;  wred[wid][1] = l;
        wred[wid][2] = a0; wred[wid][3] = a1;
        wred[wid][4] = a2; wred[wid][5] = a3;
    }
    __syncthreads();
    if (tid == 0) {
        float M = wred[0][0], L = wred[0][1];
        float A0 = wred[0][2], A1 = wred[0][3], A2 = wred[0][4], A3 = wred[0][5];
        #pragma unroll
        for (int w = 1; w < 4; ++w) {
            float m2 = wred[w][0];
            float mn = fmaxf(M, m2);
            float s1 = __expf(M - mn), s2 = __expf(m2 - mn);
            L  = L  * s1 + wred[w][1] * s2;
            A0 = A0 * s1 + wred[w][2] * s2;
            A1 = A1 * s1 + wred[w][3] * s2;
            A2 = A2 * s1 + wred[w][4] * s2;
            A3 = A3 * s1 + wred[w][5] * s2;
            M = mn;
        }
        float mean = (A0 + A1 + A2 + A3) / (4.0f * L);
        float prob = 1.0f / (1.0f + __expf(-mean));
        out[r * 2 + 0] = prob;
        out[r * 2 + 1] = 1.0f - prob;
    }
}

// ---------------------------------------------------------------------------
extern "C" void kernel_launch(void* const* d_in, const int* in_sizes, int n_in,
                              void* d_out, int out_size, void* d_ws, size_t ws_size,
                              hipStream_t stream) {
    const float* x       = (const float*)d_in[0];
    const float* conv_w  = (const float*)d_in[1];
    const float* conv_b  = (const float*)d_in[2];
    const float* embed_w = (const float*)d_in[3];
    const float* embed_b = (const float*)d_in[4];
    const float* rot     = (const float*)d_in[5];
    const float* ent     = (const float*)d_in[6];
    float* out = (float*)d_out;

    float* embedded = (float*)d_ws;          // NB*4 floats
    float* q        = embedded + NB * 4;     // NB*4 floats
    float* k        = q + NB * 4;            // NB*4 floats

    conv_embed_kernel<<<NB, 256, 0, stream>>>(x, conv_w, conv_b, embed_w,
                                              embed_b, embedded);
    qk_kernel<<<NB / 256, 256, 0, stream>>>(embedded, rot, ent, q, k);
    attn_kernel<<<NB, 256, 0, stream>>>(embedded, q, k, out);
}

// Round 3
// 98.252 us; speedup vs baseline: 1.9137x; 1.9137x over previous
//
#include <hip/hip_runtime.h>
#include <math.h>

#define HW    224
#define OW    223
#define FLAT  (OW * OW)        // 49729
#define NB    1024             // batch
#define NGRP  (OW * 56)        // 12488 groups of 4 positions (56 col-groups/row)
#define EWPK  (NGRP * 16)      // packed embed_w floats = 199808

// ---------------------------------------------------------------------------
// Kernel 0: repack embed_w [4][FLAT] -> ew_pack[g][c][4], g = i*56 + j0/4,
// zero-filled where j0+l >= 223. Makes conv inner loop fully float4-aligned.
// ---------------------------------------------------------------------------
__global__ __launch_bounds__(256) void pack_ew_kernel(
    const float* __restrict__ embed_w, float* __restrict__ ew_pack)
{
    int idx = blockIdx.x * 256 + threadIdx.x;      // one (g, c) pair
    if (idx >= NGRP * 4) return;
    int g = idx >> 2;
    int c = idx & 3;
    int i  = g / 56;
    int j0 = (g - i * 56) * 4;
    const float* src = embed_w + (size_t)c * FLAT + (size_t)i * OW + j0;
    float v0 = src[0];
    float v1 = (j0 + 1 < OW) ? src[1] : 0.f;
    float v2 = (j0 + 2 < OW) ? src[2] : 0.f;
    float v3 = (j0 + 3 < OW) ? src[3] : 0.f;
    ((float4*)(ew_pack + (size_t)g * 16 + c * 4))[0] = make_float4(v0, v1, v2, v3);
}

// ---------------------------------------------------------------------------
// Kernel 1: fused conv2d(k=2) + sigmoid + embed projection, vectorized.
// One block per image; each thread handles groups of 4 positions.
// j == 220 is the only group touching (invalid, zero-weighted) column 223;
// its edge loads would read 1 element past the image (and past the whole
// x allocation at b=1023) -> substitute 0 (exact, since e*.w == 0 there).
// ---------------------------------------------------------------------------
__global__ __launch_bounds__(256) void conv_embed_fast(
    const float* __restrict__ x, const float* __restrict__ conv_w,
    const float* __restrict__ conv_b, const float* __restrict__ ew_pack,
    const float* __restrict__ embed_b, float* __restrict__ embedded)
{
    const int b   = blockIdx.x;
    const int tid = threadIdx.x;

    const float w00 = conv_w[0], w01 = conv_w[1];
    const float w10 = conv_w[2], w11 = conv_w[3];
    const float cb  = conv_b[0];

    const float* __restrict__ xb = x + (size_t)b * (HW * HW);

    float a0 = 0.f, a1 = 0.f, a2 = 0.f, a3 = 0.f;

    // NGRP = 12488 = 48*256 + 200 : 48 full iterations + guarded tail
    #pragma unroll 4
    for (int it = 0; it < 49; ++it) {
        const int g = it * 256 + tid;
        if (it == 48 && g >= NGRP) break;
        const int i  = g / 56;
        const int j  = (g - i * 56) * 4;
        const bool edge = (j == 220);
        const float* xr = xb + i * HW + j;
        float4 t  = *(const float4*)xr;
        float  te = edge ? 0.f : xr[4];
        float4 bt = *(const float4*)(xr + HW);
        float  be = edge ? 0.f : xr[HW + 4];
        const float4* ep = (const float4*)(ew_pack + (size_t)g * 16);
        float4 e0 = ep[0], e1 = ep[1], e2 = ep[2], e3 = ep[3];

        float z0 = w00 * t.x + w01 * t.y + w10 * bt.x + w11 * bt.y + cb;
        float z1 = w00 * t.y + w01 * t.z + w10 * bt.y + w11 * bt.z + cb;
        float z2 = w00 * t.z + w01 * t.w + w10 * bt.z + w11 * bt.w + cb;
        float z3 = w00 * t.w + w01 * te  + w10 * bt.w + w11 * be  + cb;
        float s0 = 1.0f / (1.0f + __expf(-z0));
        float s1 = 1.0f / (1.0f + __expf(-z1));
        float s2 = 1.0f / (1.0f + __expf(-z2));
        float s3 = 1.0f / (1.0f + __expf(-z3));

        a0 += s0 * e0.x + s1 * e0.y + s2 * e0.z + s3 * e0.w;
        a1 += s0 * e1.x + s1 * e1.y + s2 * e1.z + s3 * e1.w;
        a2 += s0 * e2.x + s1 * e2.y + s2 * e2.z + s3 * e2.w;
        a3 += s0 * e3.x + s1 * e3.y + s2 * e3.z + s3 * e3.w;
    }

    // wave (64-lane) reduction
    #pragma unroll
    for (int off = 32; off > 0; off >>= 1) {
        a0 += __shfl_down(a0, off, 64);
        a1 += __shfl_down(a1, off, 64);
        a2 += __shfl_down(a2, off, 64);
        a3 += __shfl_down(a3, off, 64);
    }

    __shared__ float red[4][4];
    const int wid  = tid >> 6;
    const int lane = tid & 63;
    if (lane == 0) {
        red[wid][0] = a0; red[wid][1] = a1; red[wid][2] = a2; red[wid][3] = a3;
    }
    __syncthreads();
    if (tid == 0) {
        float r0 = red[0][0] + red[1][0] + red[2][0] + red[3][0] + embed_b[0];
        float r1 = red[0][1] + red[1][1] + red[2][1] + red[3][1] + embed_b[1];
        float r2 = red[0][2] + red[1][2] + red[2][2] + red[3][2] + embed_b[2];
        float r3 = red[0][3] + red[1][3] + red[2][3] + red[3][3] + embed_b[3];
        ((float4*)(embedded + (size_t)b * 4))[0] = make_float4(r0, r1, r2, r3);
    }
}

// ---------------------------------------------------------------------------
// Fallback (round-1 kernel) if ws_size is too small for the packed layout.
// ---------------------------------------------------------------------------
__global__ __launch_bounds__(256) void conv_embed_kernel(
    const float* __restrict__ x, const float* __restrict__ conv_w,
    const float* __restrict__ conv_b, const float* __restrict__ embed_w,
    const float* __restrict__ embed_b, float* __restrict__ embedded)
{
    const int b   = blockIdx.x;
    const int tid = threadIdx.x;
    const float w00 = conv_w[0], w01 = conv_w[1];
    const float w10 = conv_w[2], w11 = conv_w[3];
    const float cb  = conv_b[0];
    const float* __restrict__ xb  = x + (size_t)b * (HW * HW);
    const float* __restrict__ ew0 = embed_w;
    const float* __restrict__ ew1 = embed_w + FLAT;
    const float* __restrict__ ew2 = embed_w + 2 * FLAT;
    const float* __restrict__ ew3 = embed_w + 3 * FLAT;
    float a0 = 0.f, a1 = 0.f, a2 = 0.f, a3 = 0.f;
    for (int p = tid; p < FLAT; p += 256) {
        unsigned up = (unsigned)p;
        unsigned i  = up / 223u;
        unsigned j  = up - i * 223u;
        const float* xr = xb + i * HW + j;
        float z = w00 * xr[0] + w01 * xr[1] + w10 * xr[HW] + w11 * xr[HW + 1] + cb;
        float s = 1.0f / (1.0f + __expf(-z));
        a0 += s * ew0[p]; a1 += s * ew1[p]; a2 += s * ew2[p]; a3 += s * ew3[p];
    }
    #pragma unroll
    for (int off = 32; off > 0; off >>= 1) {
        a0 += __shfl_down(a0, off, 64);
        a1 += __shfl_down(a1, off, 64);
        a2 += __shfl_down(a2, off, 64);
        a3 += __shfl_down(a3, off, 64);
    }
    __shared__ float red[4][4];
    const int wid  = tid >> 6;
    const int lane = tid & 63;
    if (lane == 0) { red[wid][0]=a0; red[wid][1]=a1; red[wid][2]=a2; red[wid][3]=a3; }
    __syncthreads();
    if (tid == 0) {
        float r0 = red[0][0]+red[1][0]+red[2][0]+red[3][0]+embed_b[0];
        float r1 = red[0][1]+red[1][1]+red[2][1]+red[3][1]+embed_b[1];
        float r2 = red[0][2]+red[1][2]+red[2][2]+red[3][2]+embed_b[2];
        float r3 = red[0][3]+red[1][3]+red[2][3]+red[3][3]+embed_b[3];
        ((float4*)(embedded + (size_t)b * 4))[0] = make_float4(r0, r1, r2, r3);
    }
}

// ---------------------------------------------------------------------------
// Kernel 2: q = e @ rotation, k = e @ entangle
// ---------------------------------------------------------------------------
__global__ __launch_bounds__(256) void qk_kernel(
    const float* __restrict__ embedded, const float* __restrict__ rot,
    const float* __restrict__ ent, float* __restrict__ q, float* __restrict__ k)
{
    int b = blockIdx.x * 256 + threadIdx.x;
    if (b >= NB) return;
    float4 ev = ((const float4*)embedded)[b];
    float qv[4], kv[4];
    #pragma unroll
    for (int c = 0; c < 4; ++c) {
        qv[c] = ev.x * rot[0*4+c] + ev.y * rot[1*4+c] + ev.z * rot[2*4+c] + ev.w * rot[3*4+c];
        kv[c] = ev.x * ent[0*4+c] + ev.y * ent[1*4+c] + ev.z * ent[2*4+c] + ev.w * ent[3*4+c];
    }
    ((float4*)q)[b] = make_float4(qv[0], qv[1], qv[2], qv[3]);
    ((float4*)k)[b] = make_float4(kv[0], kv[1], kv[2], kv[3]);
}

// ---------------------------------------------------------------------------
// Kernel 3: per-row softmax attention + mean + sigmoid -> out [NB, 2]
// ---------------------------------------------------------------------------
__global__ __launch_bounds__(256) void attn_kernel(
    const float* __restrict__ embedded, const float* __restrict__ q,
    const float* __restrict__ k, float* __restrict__ out)
{
    __shared__ float4 k_lds[NB];
    __shared__ float4 e_lds[NB];
    const int r   = blockIdx.x;
    const int tid = threadIdx.x;

    for (int c = tid; c < NB; c += 256) {
        k_lds[c] = ((const float4*)k)[c];
        e_lds[c] = ((const float4*)embedded)[c];
    }
    __syncthreads();

    const float4 qr = ((const float4*)q)[r];

    float m = -INFINITY, l = 0.f;
    float a0 = 0.f, a1 = 0.f, a2 = 0.f, a3 = 0.f;

    for (int c = tid; c < NB; c += 256) {
        float4 kc = k_lds[c];
        float s = 0.5f * (qr.x * kc.x + qr.y * kc.y + qr.z * kc.z + qr.w * kc.w);
        float mn    = fmaxf(m, s);
        float scale = __expf(m - mn);
        float p     = __expf(s - mn);
        float4 ec = e_lds[c];
        l  = l  * scale + p;
        a0 = a0 * scale + p * ec.x;
        a1 = a1 * scale + p * ec.y;
        a2 = a2 * scale + p * ec.z;
        a3 = a3 * scale + p * ec.w;
        m = mn;
    }

    #pragma unroll
    for (int off = 32; off > 0; off >>= 1) {
        float m2 = __shfl_down(m,  off, 64);
        float l2 = __shfl_down(l,  off, 64);
        float b0 = __shfl_down(a0, off, 64);
        float b1 = __shfl_down(a1, off, 64);
        float b2 = __shfl_down(a2, off, 64);
        float b3 = __shfl_down(a3, off, 64);
        float mn = fmaxf(m, m2);
        float s1 = __expf(m - mn), s2 = __expf(m2 - mn);
        l  = l  * s1 + l2 * s2;
        a0 = a0 * s1 + b0 * s2;
        a1 = a1 * s1 + b1 * s2;
        a2 = a2 * s1 + b2 * s2;
        a3 = a3 * s1 + b3 * s2;
        m = mn;
    }

    __shared__ float wred[4][6];
    const int wid  = tid >> 6;
    const int lane = tid & 63;
    if (lane == 0) {
        wred[wid][0] = m;  wred[wid][1] = l;
        wred[wid][2] = a0; wred[wid][3] = a1;
        wred[wid][4] = a2; wred[wid][5] = a3;
    }
    __syncthreads();
    if (tid == 0) {
        float M = wred[0][0], L = wred[0][1];
        float A0 = wred[0][2], A1 = wred[0][3], A2 = wred[0][4], A3 = wred[0][5];
        #pragma unroll
        for (int w = 1; w < 4; ++w) {
            float m2 = wred[w][0];
            float mn = fmaxf(M, m2);
            float s1 = __expf(M - mn), s2 = __expf(m2 - mn);
            L  = L  * s1 + wred[w][1] * s2;
            A0 = A0 * s1 + wred[w][2] * s2;
            A1 = A1 * s1 + wred[w][3] * s2;
            A2 = A2 * s1 + wred[w][4] * s2;
            A3 = A3 * s1 + wred[w][5] * s2;
            M = mn;
        }
        float mean = (A0 + A1 + A2 + A3) / (4.0f * L);
        float prob = 1.0f / (1.0f + __expf(-mean));
        out[r * 2 + 0] = prob;
        out[r * 2 + 1] = 1.0f - prob;
    }
}

// ---------------------------------------------------------------------------
extern "C" void kernel_launch(void* const* d_in, const int* in_sizes, int n_in,
                              void* d_out, int out_size, void* d_ws, size_t ws_size,
                              hipStream_t stream) {
    const float* x       = (const float*)d_in[0];
    const float* conv_w  = (const float*)d_in[1];
    const float* conv_b  = (const float*)d_in[2];
    const float* embed_w = (const float*)d_in[3];
    const float* embed_b = (const float*)d_in[4];
    const float* rot     = (const float*)d_in[5];
    const float* ent     = (const float*)d_in[6];
    float* out = (float*)d_out;

    float* embedded = (float*)d_ws;              // NB*4 floats
    float* q        = embedded + NB * 4;         // NB*4 floats
    float* k        = q + NB * 4;                // NB*4 floats
    float* ew_pack  = k + NB * 4;                // EWPK floats

    const size_t need = (size_t)(NB * 12 + EWPK) * sizeof(float);

    if (ws_size >= need) {
        pack_ew_kernel<<<(NGRP * 4 + 255) / 256, 256, 0, stream>>>(embed_w, ew_pack);
        conv_embed_fast<<<NB, 256, 0, stream>>>(x, conv_w, conv_b, ew_pack,
                                                embed_b, embedded);
    } else {
        conv_embed_kernel<<<NB, 256, 0, stream>>>(x, conv_w, conv_b, embed_w,
                                                  embed_b, embedded);
    }
    qk_kernel<<<NB / 256, 256, 0, stream>>>(embedded, rot, ent, q, k);
    attn_kernel<<<NB, 256, 0, stream>>>(embedded, q, k, out);
}